// Round 4
// baseline (88.584 us; speedup 1.0000x reference)
//
#include <hip/hip_runtime.h>
#include <hip/hip_bf16.h>
#include <math.h>

// SpectralConv2d (FNO): B=16, Cin=Cout=32, H=W=256, MODES=16x16.
// Partial DFTs, 2 kernels, each image split into two w-halves (grid 1024,
// 4 blocks/CU) for occupancy. Lane owns 2 w-columns (float2 global traffic).
//  kF (bi,wq): T[m][wl] = sum_h x[h][wq*128+wl] e^{-2pi i m h/256} (radix-2),
//              xsubp[wq][bi][m,n] = sum_{wl} T[m][wl] e^{-2pi i n (wq*128+wl)/256}
//  kI (bo,wq): os = sum_i (xsubp[0]+xsubp[1]) * W ; U[m][wl] over its half;
//              y[h][wq*128+wl] = (1/65536) Re(sum_m U e^{+2pi i m h/256})

#define PI_F 3.14159265358979323846f

__global__ __launch_bounds__(256, 4) void kF(const float* __restrict__ x,
                                             float2* __restrict__ xsubp) {
    __shared__ float2 tw[256];
    __shared__ float4 red[4][4][64];     // [wave][m'][lane] (2 cols)  16 KB
    __shared__ float2 Ts[16][130];       // [m][wl], padded row        16.6 KB
    const int t = threadIdx.x;
    { float ang = (2.0f * PI_F / 256.0f) * (float)t;
      tw[t] = make_float2(__cosf(ang), __sinf(ang)); }
    __syncthreads();

    const int bi = blockIdx.x >> 1, wq = blockIdx.x & 1;
    const float* xp = x + (size_t)bi * 65536 + wq * 128;
    const int l = t & 63, wv = t >> 6;   // lane = w-pair, wave = h-chunk

    float Tr[2][16], Ti[2][16];
#pragma unroll
    for (int m = 0; m < 16; ++m) { Tr[0][m] = Tr[1][m] = 0.f; Ti[0][m] = Ti[1][m] = 0.f; }

    const int h0 = wv * 32;
    float2 v0 = ((const float2*)(xp + h0 * 256))[l];
    float2 v1 = ((const float2*)(xp + (h0 + 128) * 256))[l];
    for (int j = 0; j < 32; ++j) {
        const int h = h0 + j;
        const int hn = h0 + ((j + 1) & 31);          // j=31: dummy reload of h0
        float2 n0 = ((const float2*)(xp + hn * 256))[l];
        float2 n1 = ((const float2*)(xp + (hn + 128) * 256))[l];
        const float xe0 = v0.x + v1.x, xe1 = v0.y + v1.y;
        const float xo0 = v0.x - v1.x, xo1 = v0.y - v1.y;
#pragma unroll
        for (int m = 0; m < 16; ++m) {
            float2 cs = tw[(m * h) & 255];           // wave-uniform broadcast
            float a = (m & 1) ? xo0 : xe0;
            float b = (m & 1) ? xo1 : xe1;
            Tr[0][m] = fmaf(a, cs.x, Tr[0][m]);      // e^{-ia} = (cos, -sin)
            Ti[0][m] = fmaf(-a, cs.y, Ti[0][m]);
            Tr[1][m] = fmaf(b, cs.x, Tr[1][m]);
            Ti[1][m] = fmaf(-b, cs.y, Ti[1][m]);
        }
        v0 = n0; v1 = n1;
    }

    // cross-wave reduce into Ts, 4 passes x 4 m
#pragma unroll
    for (int mg = 0; mg < 4; ++mg) {
        if (mg) __syncthreads();
#pragma unroll
        for (int mm = 0; mm < 4; ++mm) {
            int m = mg * 4 + mm;
            red[wv][mm][l] = make_float4(Tr[0][m], Ti[0][m], Tr[1][m], Ti[1][m]);
        }
        __syncthreads();
        const int mm = t >> 6, idx = t & 63;
        float4 a0 = red[0][mm][idx], a1 = red[1][mm][idx];
        float4 a2 = red[2][mm][idx], a3 = red[3][mm][idx];
        *(float4*)&Ts[mg * 4 + mm][2 * idx] =
            make_float4(a0.x + a1.x + a2.x + a3.x, a0.y + a1.y + a2.y + a3.y,
                        a0.z + a1.z + a2.z + a3.z, a0.w + a1.w + a2.w + a3.w);
    }
    __syncthreads();

    // partial w-DFT over this half (actual w = wq*128 + wl)
    const int m = t >> 4, n = t & 15;
    float ang = (2.0f * PI_F / 256.0f) * (float)n;
    float c1 = __cosf(ang), s1 = __sinf(ang);
    float cr = ((n & 1) && wq) ? -1.0f : 1.0f, ci = 0.0f;  // (-1)^{n*wq}
    float ar = 0.f, ai = 0.f;
    for (int wl = 0; wl < 128; ++wl) {
        float2 Tv = Ts[m][wl];                       // 4 rows/wave, distinct banks
        ar += Tv.x * cr + Tv.y * ci;                 // * conj(rot) = e^{-i n w}
        ai += Tv.y * cr - Tv.x * ci;
        float nr = fmaf(cr, c1, -ci * s1);
        float nc = fmaf(cr, s1, ci * c1);
        cr = nr; ci = nc;
    }
    xsubp[((size_t)(wq * 512 + bi)) * 256 + t] = make_float2(ar, ai);
}

__global__ __launch_bounds__(256, 4) void kI(const float2* __restrict__ xsubp,
                                             const float* __restrict__ wr,
                                             const float* __restrict__ wi,
                                             float* __restrict__ y) {
    __shared__ float2 tw[256];
    __shared__ float2 os[256];
    __shared__ float2 U[16][130];        // [m][wl], padded            16.6 KB
    const int t = threadIdx.x;
    { float ang = (2.0f * PI_F / 256.0f) * (float)t;
      tw[t] = make_float2(__cosf(ang), __sinf(ang)); }

    const int bo = blockIdx.x >> 1, wq = blockIdx.x & 1;
    const int b = bo >> 5, o = bo & 31;

    // stage 1: channel mix over Cin (sum the two w-half partials)
    {
        const float2* xa = xsubp + (size_t)(b * 32) * 256 + t;
        const float2* xb = xa + (size_t)512 * 256;
        const float* wrp = wr + (size_t)o * 256 + t;
        const float* wip = wi + (size_t)o * 256 + t;
        float ar = 0.f, ai = 0.f;
#pragma unroll 4
        for (int i = 0; i < 32; ++i) {
            float2 p = xa[i * 256];
            float2 q = xb[i * 256];
            float xr = p.x + q.x, xi2 = p.y + q.y;
            float wre = wrp[i * 8192];
            float wim = wip[i * 8192];
            ar += xr * wre - xi2 * wim;
            ai += xr * wim + xi2 * wre;
        }
        os[t] = make_float2(ar, ai);
    }
    __syncthreads();

    // stage 2: U[m][wl] for this w-half; thread = (mh = t>>7, wl = t&127)
    {
        const int wl = t & 127, mh = t >> 7;
        const int w = wq * 128 + wl;
        float twr[16], twi[16];
#pragma unroll
        for (int n = 0; n < 16; ++n) {
            float2 cs = tw[(n * w) & 255];
            twr[n] = cs.x; twi[n] = cs.y;
        }
#pragma unroll
        for (int mm = 0; mm < 8; ++mm) {
            int m = mh * 8 + mm;
            float ur = 0.f, ui = 0.f;
#pragma unroll
            for (int n = 0; n < 16; ++n) {
                float2 ov = os[m * 16 + n];          // uniform -> broadcast
                ur += ov.x * twr[n] - ov.y * twi[n]; // * e^{+i n w}
                ui += ov.x * twi[n] + ov.y * twr[n];
            }
            U[m][wl] = make_float2(ur, ui);
        }
    }
    __syncthreads();

    // stage 3: inverse h-DFT (radix-2), lane owns 2 w-columns
    const int l = t & 63, wv = t >> 6;
    float Ur[2][16], Ui[2][16];
#pragma unroll
    for (int m = 0; m < 16; ++m) {
        float4 p = *(const float4*)&U[m][2 * l];
        Ur[0][m] = p.x; Ui[0][m] = p.y; Ur[1][m] = p.z; Ui[1][m] = p.w;
    }
    float* yp = y + (size_t)bo * 65536 + wq * 128;
    const float inv = 1.0f / 65536.0f;
    for (int j = 0; j < 32; ++j) {
        const int h = wv * 32 + j;                   // pair (h, h+128)
        float ae0 = 0.f, ae1 = 0.f, ao0 = 0.f, ao1 = 0.f;
#pragma unroll
        for (int m = 0; m < 16; ++m) {
            float2 cs = tw[(m * h) & 255];           // uniform -> broadcast
            float va = fmaf(Ur[0][m], cs.x, -Ui[0][m] * cs.y);  // Re(U e^{+ia})
            float vb = fmaf(Ur[1][m], cs.x, -Ui[1][m] * cs.y);
            if (m & 1) { ao0 += va; ao1 += vb; }
            else       { ae0 += va; ae1 += vb; }
        }
        ((float2*)(yp + h * 256))[l] =
            make_float2((ae0 + ao0) * inv, (ae1 + ao1) * inv);
        ((float2*)(yp + (h + 128) * 256))[l] =
            make_float2((ae0 - ao0) * inv, (ae1 - ao1) * inv);
    }
}

extern "C" void kernel_launch(void* const* d_in, const int* in_sizes, int n_in,
                              void* d_out, int out_size, void* d_ws, size_t ws_size,
                              hipStream_t stream) {
    const float* x  = (const float*)d_in[0];   // [16][32][256][256]
    const float* wr = (const float*)d_in[1];   // [32][32][16][16]
    const float* wi = (const float*)d_in[2];   // [32][32][16][16]
    float* y = (float*)d_out;                  // [16][32][256][256]

    float2* xsubp = (float2*)d_ws;             // [2][512][256] float2 = 2 MB

    kF<<<1024, 256, 0, stream>>>(x, xsubp);
    kI<<<1024, 256, 0, stream>>>(xsubp, wr, wi, y);
}

// Round 5
// 74.330 us; speedup vs baseline: 1.1918x; 1.1918x over previous
//
#include <hip/hip_runtime.h>
#include <hip/hip_bf16.h>
#include <math.h>

// SpectralConv2d (FNO): B=16, Cin=Cout=32, H=W=256, MODES=16x16.
// Round-3 structure (fat 4-col lanes, grid 512) + radix-2 symmetry to halve
// the LDS-broadcast-bound phases (kF w-DFT tail, kI stage-2).
//  kF (per b,i): T[m][w] = sum_h x[h][w] e^{-2pi i m h/256} (radix-2 over h),
//                P[m][p][w<128] = T[w] + (-1)^p T[w+128],
//                xsub[m][n] = sum_{w<128} P[m][n&1][w] e^{-2pi i n w/256}
//  kI (per b,o): os[m][n] = sum_i xsub*W; U[m][w0],U[m][w0+128] from one
//                os*tw product; y = (1/65536) Re(sum_m U e^{+2pi i m h/256})

#define PI_F 3.14159265358979323846f

__global__ __launch_bounds__(256, 2) void kF(const float* __restrict__ x,
                                             float2* __restrict__ xsub) {
    __shared__ float2 tw[256];
    __shared__ float2 Ts[16][4][65];     // [m][c][l], w = 4l+c, padded  33.3 KB
    __shared__ float2 redP[4128];        // union: red[4][4][4][64] / P[16][2][129]
    auto red = reinterpret_cast<float2 (*)[4][4][64]>(redP);
    auto P   = reinterpret_cast<float2 (*)[2][129]>(redP);

    const int t = threadIdx.x;
    { float ang = (2.0f * PI_F / 256.0f) * (float)t;
      tw[t] = make_float2(__cosf(ang), __sinf(ang)); }
    __syncthreads();

    const int bi = blockIdx.x;
    const float* xp = x + (size_t)bi * 65536;
    const int l = t & 63, wv = t >> 6;   // lane: w = 4l..4l+3; wave = h-chunk

    float Tr[4][16], Ti[4][16];
#pragma unroll
    for (int c = 0; c < 4; ++c)
#pragma unroll
        for (int m = 0; m < 16; ++m) { Tr[c][m] = 0.0f; Ti[c][m] = 0.0f; }

#pragma unroll 2
    for (int j = 0; j < 32; ++j) {
        const int h = wv * 32 + j;       // h-pair (h, h+128)
        const float4 v0 = ((const float4*)(xp + h * 256))[l];
        const float4 v1 = ((const float4*)(xp + (h + 128) * 256))[l];
        const float xe[4] = {v0.x + v1.x, v0.y + v1.y, v0.z + v1.z, v0.w + v1.w};
        const float xo[4] = {v0.x - v1.x, v0.y - v1.y, v0.z - v1.z, v0.w - v1.w};
#pragma unroll
        for (int m = 0; m < 16; ++m) {
            float2 cs = tw[(m * h) & 255];           // wave-uniform broadcast
#pragma unroll
            for (int c = 0; c < 4; ++c) {
                float xv = (m & 1) ? xo[c] : xe[c];
                Tr[c][m] = fmaf(xv, cs.x, Tr[c][m]); // e^{-ia} = (cos, -sin)
                Ti[c][m] = fmaf(-xv, cs.y, Ti[c][m]);
            }
        }
    }

    // cross-wave reduce into Ts, 4 m-groups of 4
#pragma unroll
    for (int mg = 0; mg < 4; ++mg) {
        if (mg) __syncthreads();
#pragma unroll
        for (int mm = 0; mm < 4; ++mm)
#pragma unroll
            for (int c = 0; c < 4; ++c)
                red[wv][mm][c][l] = make_float2(Tr[c][mg * 4 + mm], Ti[c][mg * 4 + mm]);
        __syncthreads();
        const int mq = t >> 6, idx = t & 63;
#pragma unroll
        for (int c = 0; c < 4; ++c) {
            float2 a0 = red[0][mq][c][idx], a1 = red[1][mq][c][idx];
            float2 a2 = red[2][mq][c][idx], a3 = red[3][mq][c][idx];
            Ts[mg * 4 + mq][c][idx] =
                make_float2(a0.x + a1.x + a2.x + a3.x, a0.y + a1.y + a2.y + a3.y);
        }
    }
    __syncthreads();                      // red no longer live; P may overwrite

    // parity precombine: P[m][p][w] = T[m][w] + (-1)^p T[m][w+128], w<128
#pragma unroll
    for (int k = 0; k < 8; ++k) {
        const int s = k * 256 + t;        // 16m x 128w slots
        const int m = s >> 7, w = s & 127;
        const int c = w & 3, li = w >> 2; // w = 4*li + c; w+128 -> li+32
        float2 A = Ts[m][c][li], Bv = Ts[m][c][li + 32];
        P[m][0][w] = make_float2(A.x + Bv.x, A.y + Bv.y);
        P[m][1][w] = make_float2(A.x - Bv.x, A.y - Bv.y);
    }
    __syncthreads();

    // w-DFT tail: thread (m = t>>4, n = t&15), 128 iters on parity plane
    const int m = t >> 4, n = t & 15;
    const float2* Pp = &P[m][n & 1][0];
    float ang = (2.0f * PI_F / 256.0f) * (float)n;
    float c1 = __cosf(ang), s1 = __sinf(ang);
    float cr = 1.0f, ci = 0.0f;
    float ar = 0.0f, ai = 0.0f;
    for (int w = 0; w < 128; ++w) {
        float2 Tv = Pp[w];               // 8 distinct banks/wave, broadcast
        ar += Tv.x * cr + Tv.y * ci;     // * e^{-i n w}
        ai += Tv.y * cr - Tv.x * ci;
        float nr = fmaf(cr, c1, -ci * s1);
        float nc = fmaf(cr, s1, ci * c1);
        cr = nr; ci = nc;
    }
    xsub[(size_t)bi * 256 + t] = make_float2(ar, ai);
}

__global__ __launch_bounds__(256, 2) void kI(const float2* __restrict__ xsub,
                                             const float* __restrict__ wr,
                                             const float* __restrict__ wi,
                                             float* __restrict__ y) {
    __shared__ float2 tw[256];
    __shared__ float2 os[256];
    __shared__ float2 U[16][256];        // 32 KB
    const int t = threadIdx.x;
    { float ang = (2.0f * PI_F / 256.0f) * (float)t;
      tw[t] = make_float2(__cosf(ang), __sinf(ang)); }

    const int bo = blockIdx.x, b = bo >> 5, o = bo & 31;

    // stage 1: channel mix over Cin
    {
        float ar = 0.0f, ai = 0.0f;
#pragma unroll 4
        for (int i = 0; i < 32; ++i) {
            float2 xv = xsub[(size_t)(b * 32 + i) * 256 + t];
            float wre = wr[(size_t)(i * 32 + o) * 256 + t];
            float wim = wi[(size_t)(i * 32 + o) * 256 + t];
            ar += xv.x * wre - xv.y * wim;
            ai += xv.x * wim + xv.y * wre;
        }
        os[t] = make_float2(ar, ai);
    }
    __syncthreads();

    // stage 2: radix-2 over w: thread (mh = t>>7, w0 = t&127) fills
    // U[m][w0] and U[m][w0+128] from one os*tw product ((-1)^n sign)
    {
        const int w0 = t & 127, mh = t >> 7;
        float twr[16], twi[16];
#pragma unroll
        for (int n = 0; n < 16; ++n) {
            float2 cs = tw[(n * w0) & 255];
            twr[n] = cs.x; twi[n] = cs.y;
        }
#pragma unroll
        for (int mm = 0; mm < 8; ++mm) {
            const int m = mh * 8 + mm;
            float u0r = 0.f, u0i = 0.f, u1r = 0.f, u1i = 0.f;
#pragma unroll
            for (int n = 0; n < 16; ++n) {
                float2 ov = os[m * 16 + n];          // uniform -> broadcast
                float tr = ov.x * twr[n] - ov.y * twi[n];   // * e^{+i n w0}
                float ti2 = ov.x * twi[n] + ov.y * twr[n];
                u0r += tr; u0i += ti2;
                if (n & 1) { u1r -= tr; u1i -= ti2; }
                else       { u1r += tr; u1i += ti2; }
            }
            U[m][w0]       = make_float2(u0r, u0i);
            U[m][w0 + 128] = make_float2(u1r, u1i);
        }
    }
    __syncthreads();

    // stage 3: inverse h-DFT (radix-2 over h), lane owns w = 4l..4l+3
    const int l = t & 63, wv = t >> 6;
    float Ur[4][16], Ui[4][16];
#pragma unroll
    for (int m = 0; m < 16; ++m) {
        const float4* Um = (const float4*)&U[m][0];
        float4 p0 = Um[2 * l], p1 = Um[2 * l + 1];
        Ur[0][m] = p0.x; Ui[0][m] = p0.y; Ur[1][m] = p0.z; Ui[1][m] = p0.w;
        Ur[2][m] = p1.x; Ui[2][m] = p1.y; Ur[3][m] = p1.z; Ui[3][m] = p1.w;
    }

    float* yp = y + (size_t)bo * 65536;
    const float inv = 1.0f / 65536.0f;
#pragma unroll 2
    for (int j = 0; j < 32; ++j) {
        const int h = wv * 32 + j;       // h-pair (h, h+128)
        float ae[4] = {0, 0, 0, 0}, ao[4] = {0, 0, 0, 0};
#pragma unroll
        for (int m = 0; m < 16; ++m) {
            float2 cs = tw[(m * h) & 255];           // uniform -> broadcast
#pragma unroll
            for (int c = 0; c < 4; ++c) {
                float v = fmaf(Ur[c][m], cs.x, -Ui[c][m] * cs.y); // Re(U e^{+ia})
                if (m & 1) ao[c] += v; else ae[c] += v;
            }
        }
        float4 ye, yo2;
        ye.x = (ae[0] + ao[0]) * inv; ye.y = (ae[1] + ao[1]) * inv;
        ye.z = (ae[2] + ao[2]) * inv; ye.w = (ae[3] + ao[3]) * inv;
        yo2.x = (ae[0] - ao[0]) * inv; yo2.y = (ae[1] - ao[1]) * inv;
        yo2.z = (ae[2] - ao[2]) * inv; yo2.w = (ae[3] - ao[3]) * inv;
        ((float4*)(yp + h * 256))[l] = ye;
        ((float4*)(yp + (h + 128) * 256))[l] = yo2;
    }
}

extern "C" void kernel_launch(void* const* d_in, const int* in_sizes, int n_in,
                              void* d_out, int out_size, void* d_ws, size_t ws_size,
                              hipStream_t stream) {
    const float* x  = (const float*)d_in[0];   // [16][32][256][256]
    const float* wr = (const float*)d_in[1];   // [32][32][16][16]
    const float* wi = (const float*)d_in[2];   // [32][32][16][16]
    float* y = (float*)d_out;                  // [16][32][256][256]

    float2* xsub = (float2*)d_ws;              // 512*256*8 = 1 MB

    kF<<<512, 256, 0, stream>>>(x, xsub);
    kI<<<512, 256, 0, stream>>>(xsub, wr, wi, y);
}